// Round 5
// baseline (206.423 us; speedup 1.0000x reference)
//
#include <hip/hip_runtime.h>
#include <math.h>

// B=2, HD=4, H=W=128, KSIZE=7 (K=49), NSP=9, S=64
#define BN   2
#define HDN  4
#define HN   128
#define WN   128
#define KS   7
#define KK   49
#define NSPN 9
#define SN   64
#define PPW  8       // pixels per wave
#define WVS  2       // waves per block
#define TPB  128
#define PROW 56      // row stride: float4 chunks conflict-free mod 32
#define NH   28      // taps per half (half1: 21 real + 7 zero pads)

// Lane layout: lane = pix*8 + hd*2 + half. Lane pairs (^1) share (pixel,hd),
// split 49 taps 28/21 -> K-work is serial register FMA; cross-lane ops are
// two __shfl_xor(.,1) per (sp,head). Staging is wave-local; __syncthreads()
// at the three LDS ordering points is the compiler/HW fence (R4 lacked it ->
// scheduler hoisted float4 ds_reads above float ds_writes -> stale buffer).
__global__ __launch_bounds__(TPB, 4) void attn_rw5(
    const float* __restrict__ attn,
    const float* __restrict__ sims,
    const int*   __restrict__ sinds,
    float*       __restrict__ out)
{
    __shared__ __align__(16) float pbuf[WVS][2][PPW * PROW];  // 7168 B
    __shared__ int   g_lds[WVS][PPW * NSPN];
    __shared__ float pi_lds[WVS][PPW * NSPN];

    const int t    = threadIdx.x;
    const int lane = t & 63;
    const int wv   = t >> 6;
    const int bx   = blockIdx.x;
    const int wseg = bx & 7;                  // 8 segs x 16 px
    const int hh   = (bx >> 3) & 127;
    const int b    = bx >> 10;
    const int ww0  = wseg * 16 + wv * PPW;    // this wave's first pixel

    const int pix  = lane >> 3;               // 0..7
    const int hd   = (lane >> 1) & 3;
    const int half = lane & 1;
    const int ww   = ww0 + pix;

    const float* simsB = sims + ((size_t)b << 20);
    int hs = hh - 3; hs = max(0, min(HN - KS, hs));   // uniform per block

    // ---- per-thread attn half: issue loads first (longest latency) ----
    const int  kbase = half * NH;             // 0 or 28
    const int  nk    = half ? (KK - NH) : NH; // 28 or 21
    float av[NH];
    const size_t abase =
        ((((size_t)b * HDN + hd) * HN + hh) * WN + ww) * (size_t)KK + kbase;
    #pragma unroll
    for (int j = 0; j < NH; ++j)
        av[j] = (j < nk) ? attn[abase + j] : -INFINITY;

    // ---- wave-local staging: pads, g, pi ----
    {
        float* pw = (float*)pbuf[wv];
        for (int e = lane; e < 2 * PPW * 7; e += 64) {
            int row = e / 7, off = 49 + e % 7;
            pw[row * PROW + off] = 0.0f;
        }
    }
    const int sbase = ((b * HN + hh) * WN + ww0) * NSPN;   // 72 contiguous ints
    for (int e = lane; e < PPW * NSPN; e += 64) {
        int g = sinds[sbase + e];
        g_lds[wv][e] = g;
        pi_lds[wv][e] = simsB[(g << 14) + hh * WN + ww0 + e / NSPN];
    }

    // ---- finish attn: pair-max, exp ----
    float m = av[0];
    #pragma unroll
    for (int j = 1; j < NH; ++j) m = fmaxf(m, av[j]);
    m = fmaxf(m, __shfl_xor(m, 1));           // full 49-tap max
    #pragma unroll
    for (int j = 0; j < NH; ++j) av[j] = __expf(av[j] - m);  // pads -> 0

    __syncthreads();   // staging (g/pi/pads) visible before any pbuf/g reads

    // ---- gather helpers (lane<49 <-> tap) ----
    const int  gki     = lane / KS;
    const int  gkj     = lane - gki * KS;
    const int  laneoff = gki * WN + gkj;
    const bool gact    = lane < KK;

    auto gload = [&](int sp, float r[PPW]) {
        #pragma unroll
        for (int i = 0; i < PPW; ++i) {
            int g  = g_lds[wv][i * NSPN + sp];          // wave-uniform broadcast
            int ws = ww0 + i - 3; ws = max(0, min(WN - KS, ws));
            const float* src = simsB + ((size_t)g << 14) + hs * WN + ws;
            r[i] = gact ? src[laneoff] : 0.0f;
        }
    };
    auto gstore = [&](int buf, const float r[PPW]) {
        if (gact) {
            #pragma unroll
            for (int i = 0; i < PPW; ++i)
                pbuf[wv][buf][i * PROW + lane] = r[i];
        }
    };

    float r0[PPW];
    gload(0, r0);
    gstore(0, r0);
    __syncthreads();   // pbuf[0] visible

    float acc[NH];
    #pragma unroll
    for (int j = 0; j < NH; ++j) acc[j] = 0.0f;

    for (int sp = 0; sp < NSPN; ++sp) {
        const int buf = sp & 1;
        if (sp > 0) __syncthreads();   // publish gstore(sp-1) -> pbuf[buf]

        float rn[PPW];
        if (sp + 1 < NSPN) gload(sp + 1, rn);   // loads in flight over compute

        const float4* pr = (const float4*)&pbuf[wv][buf][pix * PROW + kbase];

        // denom partial (4-way chains)
        float d0 = 0.f, d1 = 0.f, d2 = 0.f, d3 = 0.f;
        #pragma unroll
        for (int q = 0; q < NH / 4; ++q) {
            float4 v = pr[q];
            d0 = fmaf(av[q * 4 + 0], v.x, d0);
            d1 = fmaf(av[q * 4 + 1], v.y, d1);
            d2 = fmaf(av[q * 4 + 2], v.z, d2);
            d3 = fmaf(av[q * 4 + 3], v.w, d3);
        }
        float d = (d0 + d1) + (d2 + d3);
        d += __shfl_xor(d, 1);                   // full 49-tap denom

        float pi   = pi_lds[wv][pix * NSPN + sp];
        float coef = pi * __builtin_amdgcn_rcpf(d + 1e-10f);

        #pragma unroll
        for (int q = 0; q < NH / 4; ++q) {
            float4 v = pr[q];
            acc[q * 4 + 0] = fmaf(coef, v.x, acc[q * 4 + 0]);
            acc[q * 4 + 1] = fmaf(coef, v.y, acc[q * 4 + 1]);
            acc[q * 4 + 2] = fmaf(coef, v.z, acc[q * 4 + 2]);
            acc[q * 4 + 3] = fmaf(coef, v.w, acc[q * 4 + 3]);
        }

        if (sp + 1 < NSPN) gstore(buf ^ 1, rn);  // ds_write after compute ds_reads
    }

    // ---- epilogue: out = a * acc, contiguous per lane pair ----
    #pragma unroll
    for (int j = 0; j < NH; ++j)
        if (j < nk) out[abase + j] = av[j] * acc[j];
}

extern "C" void kernel_launch(void* const* d_in, const int* in_sizes, int n_in,
                              void* d_out, int out_size, void* d_ws, size_t ws_size,
                              hipStream_t stream) {
    const float* attn  = (const float*)d_in[0];
    const float* sims  = (const float*)d_in[1];
    const int*   sinds = (const int*)d_in[2];
    float*       outp  = (float*)d_out;

    // blocks: b(2) x hh(128) x wseg(8) = 2048, 128 threads (2 waves)
    const int blocks = BN * HN * (WN / (PPW * WVS));
    attn_rw5<<<blocks, TPB, 0, stream>>>(attn, sims, sinds, outp);
}

// Round 6
// 141.777 us; speedup vs baseline: 1.4560x; 1.4560x over previous
//
#include <hip/hip_runtime.h>
#include <math.h>

// B=2, HD=4, H=W=128, KSIZE=7 (K=49), NSP=9, S=64
#define BN   2
#define HDN  4
#define HN   128
#define WN   128
#define KS   7
#define KK   49
#define NSPN 9
#define SN   64
#define PPW  8       // pixels per wave
#define WVS  2       // waves per block
#define TPB  128
#define PROW 56      // row stride: float4 chunks conflict-free mod 32
#define NH   28      // taps per half (half1: 21 real + 7 zero pads)

// Lane layout: lane = pix*8 + hd*2 + half. Lane pairs (^1) share (pixel,hd),
// split 49 taps 28/21 -> K-work is serial register FMA; cross-lane ops are
// two __shfl_xor(.,1) per (sp,head).
// __launch_bounds__(128,2): R5 used (128,4) which capped VGPRs at 64 ->
// scratch spills (FETCH 163MB / WRITE 230MB, 9x amplification). Live set is
// ~80 VGPRs (av[28]+acc[28]+rn[8]); (128,2) gives ~100 like R2, no spill.
__global__ __launch_bounds__(TPB, 2) void attn_rw6(
    const float* __restrict__ attn,
    const float* __restrict__ sims,
    const int*   __restrict__ sinds,
    float*       __restrict__ out)
{
    __shared__ __align__(16) float pbuf[WVS][2][PPW * PROW];  // 7168 B
    __shared__ int   g_lds[WVS][PPW * NSPN];
    __shared__ float pi_lds[WVS][PPW * NSPN];

    const int t    = threadIdx.x;
    const int lane = t & 63;
    const int wv   = t >> 6;
    const int bx   = blockIdx.x;
    const int wseg = bx & 7;                  // 8 segs x 16 px
    const int hh   = (bx >> 3) & 127;
    const int b    = bx >> 10;
    const int ww0  = wseg * 16 + wv * PPW;    // this wave's first pixel

    const int pix  = lane >> 3;               // 0..7
    const int hd   = (lane >> 1) & 3;
    const int half = lane & 1;
    const int ww   = ww0 + pix;

    const float* simsB = sims + ((size_t)b << 20);
    int hs = hh - 3; hs = max(0, min(HN - KS, hs));   // uniform per block

    // ---- per-thread attn half: issue loads first (longest latency) ----
    const int  kbase = half * NH;             // 0 or 28
    const int  nk    = half ? (KK - NH) : NH; // 28 or 21
    float av[NH];
    const size_t abase =
        ((((size_t)b * HDN + hd) * HN + hh) * WN + ww) * (size_t)KK + kbase;
    #pragma unroll
    for (int j = 0; j < NH; ++j)
        av[j] = (j < nk) ? attn[abase + j] : -INFINITY;

    // ---- wave-local staging: pads, g, pi ----
    {
        float* pw = (float*)pbuf[wv];
        for (int e = lane; e < 2 * PPW * 7; e += 64) {
            int row = e / 7, off = 49 + e % 7;
            pw[row * PROW + off] = 0.0f;
        }
    }
    const int sbase = ((b * HN + hh) * WN + ww0) * NSPN;   // 72 contiguous ints
    for (int e = lane; e < PPW * NSPN; e += 64) {
        int g = sinds[sbase + e];
        g_lds[wv][e] = g;
        pi_lds[wv][e] = simsB[(g << 14) + hh * WN + ww0 + e / NSPN];
    }

    // ---- finish attn: pair-max, exp ----
    float m = av[0];
    #pragma unroll
    for (int j = 1; j < NH; ++j) m = fmaxf(m, av[j]);
    m = fmaxf(m, __shfl_xor(m, 1));           // full 49-tap max
    #pragma unroll
    for (int j = 0; j < NH; ++j) av[j] = __expf(av[j] - m);  // pads -> 0

    __syncthreads();   // staging (g/pi/pads) visible before any pbuf/g reads

    // ---- gather helpers (lane<49 <-> tap) ----
    const int  gki     = lane / KS;
    const int  gkj     = lane - gki * KS;
    const int  laneoff = gki * WN + gkj;
    const bool gact    = lane < KK;

    auto gload = [&](int sp, float r[PPW]) {
        #pragma unroll
        for (int i = 0; i < PPW; ++i) {
            int g  = g_lds[wv][i * NSPN + sp];          // wave-uniform broadcast
            int ws = ww0 + i - 3; ws = max(0, min(WN - KS, ws));
            const float* src = simsB + ((size_t)g << 14) + hs * WN + ws;
            r[i] = gact ? src[laneoff] : 0.0f;
        }
    };
    auto gstore = [&](int buf, const float r[PPW]) {
        if (gact) {
            #pragma unroll
            for (int i = 0; i < PPW; ++i)
                pbuf[wv][buf][i * PROW + lane] = r[i];
        }
    };

    float r0[PPW];
    gload(0, r0);
    gstore(0, r0);
    __syncthreads();   // pbuf[0] visible

    float acc[NH];
    #pragma unroll
    for (int j = 0; j < NH; ++j) acc[j] = 0.0f;

    for (int sp = 0; sp < NSPN; ++sp) {
        const int buf = sp & 1;
        if (sp > 0) __syncthreads();   // publish gstore(sp-1) -> pbuf[buf]

        float rn[PPW];
        if (sp + 1 < NSPN) gload(sp + 1, rn);   // loads in flight over compute

        const float4* pr = (const float4*)&pbuf[wv][buf][pix * PROW + kbase];

        // denom partial (4-way chains)
        float d0 = 0.f, d1 = 0.f, d2 = 0.f, d3 = 0.f;
        #pragma unroll
        for (int q = 0; q < NH / 4; ++q) {
            float4 v = pr[q];
            d0 = fmaf(av[q * 4 + 0], v.x, d0);
            d1 = fmaf(av[q * 4 + 1], v.y, d1);
            d2 = fmaf(av[q * 4 + 2], v.z, d2);
            d3 = fmaf(av[q * 4 + 3], v.w, d3);
        }
        float d = (d0 + d1) + (d2 + d3);
        d += __shfl_xor(d, 1);                   // full 49-tap denom

        float pi   = pi_lds[wv][pix * NSPN + sp];
        float coef = pi * __builtin_amdgcn_rcpf(d + 1e-10f);

        #pragma unroll
        for (int q = 0; q < NH / 4; ++q) {
            float4 v = pr[q];
            acc[q * 4 + 0] = fmaf(coef, v.x, acc[q * 4 + 0]);
            acc[q * 4 + 1] = fmaf(coef, v.y, acc[q * 4 + 1]);
            acc[q * 4 + 2] = fmaf(coef, v.z, acc[q * 4 + 2]);
            acc[q * 4 + 3] = fmaf(coef, v.w, acc[q * 4 + 3]);
        }

        if (sp + 1 < NSPN) gstore(buf ^ 1, rn);  // ds_write after compute ds_reads
    }

    // ---- epilogue: out = a * acc, contiguous per lane pair ----
    #pragma unroll
    for (int j = 0; j < NH; ++j)
        if (j < nk) out[abase + j] = av[j] * acc[j];
}

extern "C" void kernel_launch(void* const* d_in, const int* in_sizes, int n_in,
                              void* d_out, int out_size, void* d_ws, size_t ws_size,
                              hipStream_t stream) {
    const float* attn  = (const float*)d_in[0];
    const float* sims  = (const float*)d_in[1];
    const int*   sinds = (const int*)d_in[2];
    float*       outp  = (float*)d_out;

    // blocks: b(2) x hh(128) x wseg(8) = 2048, 128 threads (2 waves)
    const int blocks = BN * HN * (WN / (PPW * WVS));
    attn_rw6<<<blocks, TPB, 0, stream>>>(attn, sims, sinds, outp);
}

// Round 7
// 133.641 us; speedup vs baseline: 1.5446x; 1.0609x over previous
//
#include <hip/hip_runtime.h>
#include <math.h>

// B=2, HD=4, H=W=128, KSIZE=7 (K=49), NSP=9, S=64
#define BN   2
#define HDN  4
#define HN   128
#define WN   128
#define KS   7
#define KK   49
#define NSPN 9
#define SN   64
#define PPW  8       // pixels per wave
#define WVS  2       // waves per block
#define TPB  128
#define PROW 56      // row stride: float4 chunks conflict-free mod 32
#define NH   28      // taps per half (half1: 21 real + 7 zero pads)

typedef float vfloat8 __attribute__((ext_vector_type(8)));

// Lane layout: lane = pix*8 + hd*2 + half. Lane pairs (^1) share (pixel,hd),
// split 49 taps 28/21 -> K-work is serial register FMA; cross-lane ops are
// two __shfl_xor(.,1) per (sp,head).
// R6 bug: gather staging passed float[8] through a lambda param -> pointer
// decay -> alloca -> scratch (79MB writes!). float8 vector BY VALUE is SSA,
// never alloca'd.
__global__ __launch_bounds__(TPB, 2) void attn_rw7(
    const float* __restrict__ attn,
    const float* __restrict__ sims,
    const int*   __restrict__ sinds,
    float*       __restrict__ out)
{
    __shared__ __align__(16) float pbuf[WVS][2][PPW * PROW];  // 7168 B
    __shared__ int   g_lds[WVS][PPW * NSPN];
    __shared__ float pi_lds[WVS][PPW * NSPN];

    const int t    = threadIdx.x;
    const int lane = t & 63;
    const int wv   = t >> 6;
    const int bx   = blockIdx.x;
    const int wseg = bx & 7;                  // 8 segs x 16 px
    const int hh   = (bx >> 3) & 127;
    const int b    = bx >> 10;
    const int ww0  = wseg * 16 + wv * PPW;    // this wave's first pixel

    const int pix  = lane >> 3;               // 0..7
    const int hd   = (lane >> 1) & 3;
    const int half = lane & 1;
    const int ww   = ww0 + pix;

    const float* simsB = sims + ((size_t)b << 20);
    int hs = hh - 3; hs = max(0, min(HN - KS, hs));   // uniform per block

    // ---- per-thread attn half: issue loads first (longest latency) ----
    const int  kbase = half * NH;             // 0 or 28
    const int  nk    = half ? (KK - NH) : NH; // 28 or 21
    float av[NH];
    const size_t abase =
        ((((size_t)b * HDN + hd) * HN + hh) * WN + ww) * (size_t)KK + kbase;
    #pragma unroll
    for (int j = 0; j < NH; ++j)
        av[j] = (j < nk) ? attn[abase + j] : -INFINITY;

    // ---- wave-local staging: pads, g, pi ----
    {
        float* pw = (float*)pbuf[wv];
        for (int e = lane; e < 2 * PPW * 7; e += 64) {
            int row = e / 7, off = 49 + e % 7;
            pw[row * PROW + off] = 0.0f;
        }
    }
    const int sbase = ((b * HN + hh) * WN + ww0) * NSPN;   // 72 contiguous ints
    for (int e = lane; e < PPW * NSPN; e += 64) {
        int g = sinds[sbase + e];
        g_lds[wv][e] = g;
        pi_lds[wv][e] = simsB[(g << 14) + hh * WN + ww0 + e / NSPN];
    }

    // ---- finish attn: pair-max, exp ----
    float m = av[0];
    #pragma unroll
    for (int j = 1; j < NH; ++j) m = fmaxf(m, av[j]);
    m = fmaxf(m, __shfl_xor(m, 1));           // full 49-tap max
    #pragma unroll
    for (int j = 0; j < NH; ++j) av[j] = __expf(av[j] - m);  // pads -> 0

    __syncthreads();   // staging (g/pi/pads) visible before any pbuf/g reads

    // ---- gather helpers (lane<49 <-> tap) ----
    const int  gki     = lane / KS;
    const int  gkj     = lane - gki * KS;
    const int  laneoff = gki * WN + gkj;
    const bool gact    = lane < KK;

    auto gload = [&](int sp) -> vfloat8 {
        vfloat8 r;
        #pragma unroll
        for (int i = 0; i < PPW; ++i) {
            int g  = g_lds[wv][i * NSPN + sp];          // wave-uniform broadcast
            int ws = ww0 + i - 3; ws = max(0, min(WN - KS, ws));
            const float* src = simsB + ((size_t)g << 14) + hs * WN + ws;
            r[i] = gact ? src[laneoff] : 0.0f;
        }
        return r;
    };
    auto gstore = [&](int buf, vfloat8 r) {
        if (gact) {
            #pragma unroll
            for (int i = 0; i < PPW; ++i)
                pbuf[wv][buf][i * PROW + lane] = r[i];
        }
    };

    gstore(0, gload(0));
    __syncthreads();   // pbuf[0] visible

    float acc[NH];
    #pragma unroll
    for (int j = 0; j < NH; ++j) acc[j] = 0.0f;

    for (int sp = 0; sp < NSPN; ++sp) {
        const int buf = sp & 1;
        if (sp > 0) __syncthreads();   // publish gstore(sp-1) -> pbuf[buf]

        vfloat8 rn;
        if (sp + 1 < NSPN) rn = gload(sp + 1);   // loads in flight over compute

        const float4* pr = (const float4*)&pbuf[wv][buf][pix * PROW + kbase];

        // denom partial (4-way chains)
        float d0 = 0.f, d1 = 0.f, d2 = 0.f, d3 = 0.f;
        #pragma unroll
        for (int q = 0; q < NH / 4; ++q) {
            float4 v = pr[q];
            d0 = fmaf(av[q * 4 + 0], v.x, d0);
            d1 = fmaf(av[q * 4 + 1], v.y, d1);
            d2 = fmaf(av[q * 4 + 2], v.z, d2);
            d3 = fmaf(av[q * 4 + 3], v.w, d3);
        }
        float d = (d0 + d1) + (d2 + d3);
        d += __shfl_xor(d, 1);                   // full 49-tap denom

        float pi   = pi_lds[wv][pix * NSPN + sp];
        float coef = pi * __builtin_amdgcn_rcpf(d + 1e-10f);

        #pragma unroll
        for (int q = 0; q < NH / 4; ++q) {
            float4 v = pr[q];
            acc[q * 4 + 0] = fmaf(coef, v.x, acc[q * 4 + 0]);
            acc[q * 4 + 1] = fmaf(coef, v.y, acc[q * 4 + 1]);
            acc[q * 4 + 2] = fmaf(coef, v.z, acc[q * 4 + 2]);
            acc[q * 4 + 3] = fmaf(coef, v.w, acc[q * 4 + 3]);
        }

        if (sp + 1 < NSPN) gstore(buf ^ 1, rn);  // ds_write after compute ds_reads
    }

    // ---- epilogue: out = a * acc, contiguous per lane pair ----
    #pragma unroll
    for (int j = 0; j < NH; ++j)
        if (j < nk) out[abase + j] = av[j] * acc[j];
}

extern "C" void kernel_launch(void* const* d_in, const int* in_sizes, int n_in,
                              void* d_out, int out_size, void* d_ws, size_t ws_size,
                              hipStream_t stream) {
    const float* attn  = (const float*)d_in[0];
    const float* sims  = (const float*)d_in[1];
    const int*   sinds = (const int*)d_in[2];
    float*       outp  = (float*)d_out;

    // blocks: b(2) x hh(128) x wseg(8) = 2048, 128 threads (2 waves)
    const int blocks = BN * HN * (WN / (PPW * WVS));
    attn_rw7<<<blocks, TPB, 0, stream>>>(attn, sims, sinds, outp);
}